// Round 7
// baseline (329.594 us; speedup 1.0000x reference)
//
#include <hip/hip_runtime.h>
#include <math.h>

// Problem constants
#define MROWS   16384      // B*N
#define KCODES  8192
#define CDIM    256

// d_out layout (floats): [quantized 4194304][loss 1][indices 16384]
#define LOSS_OFF 4194304
#define IDXOFF   4194305

// ---- ws byte layout (~13.7 MB) ----
#define NSPLIT  4
#define WS_ZH   0                                   // f16 z plane, 8.39 MB
#define WS_EH   (WS_ZH + MROWS * CDIM * 2)          // f16 E plane, 4.19 MB
#define WS_EN   (WS_EH + KCODES * CDIM * 2)         // float[8192]
#define WS_C    (WS_EN + KCODES * 4)                // per row x split: {v1,i1,v2,i2} 16 B
#define WS_PB   (WS_C + MROWS * NSPLIT * 16)        // float[4096] block loss partials

// Pass-1 tiling: block = 128 thr = 2 waves; block tile 64 rows x one split
// (2048 codes); per barrier segment one 32-code x 256-half E tile (16 KB).
// Each wave owns 32 rows, full-K f16 A-fragments in registers (64 VGPRs).
#define BNT 32
#define CODES_PER_SPLIT (KCODES / NSPLIT)   // 2048
#define NTILES (CODES_PER_SPLIT / BNT)      // 64

typedef float    v4f __attribute__((ext_vector_type(4)));
typedef _Float16 v8h __attribute__((ext_vector_type(8)));
typedef _Float16 v4h __attribute__((ext_vector_type(4)));

__device__ __forceinline__ void gload_lds16(const void* g, void* l) {
    __builtin_amdgcn_global_load_lds(
        (const __attribute__((address_space(1))) void*)g,
        (__attribute__((address_space(3))) void*)l, 16, 0, 0);
}

// ---------------------------------------------------------------------------
// Kernel 1: convert fp32 -> f16 plane for z and emb; ||e||^2 (fp32 exact).
__global__ void convert_enorm_kernel(const float* __restrict__ z,
                                     const float* __restrict__ emb,
                                     char* __restrict__ ws) {
    int tid = threadIdx.x;
    int w = tid >> 6, l = tid & 63;
    int row = blockIdx.x * 4 + w;
    const float4* src;
    _Float16* hp;
    bool isE = (row >= MROWS);
    int u = row - MROWS;
    if (!isE) {
        src = (const float4*)(z + (size_t)row * CDIM);
        hp = (_Float16*)(ws + WS_ZH) + (size_t)row * CDIM;
    } else {
        src = (const float4*)(emb + (size_t)u * CDIM);
        hp = (_Float16*)(ws + WS_EH) + (size_t)u * CDIM;
    }
    float4 v = src[l];
    v4h h;
    h.x = (_Float16)v.x; h.y = (_Float16)v.y;
    h.z = (_Float16)v.z; h.w = (_Float16)v.w;
    *(v4h*)(hp + l * 4) = h;
    if (isE) {
        float s = v.x * v.x + v.y * v.y + v.z * v.z + v.w * v.w;
#pragma unroll
        for (int m = 32; m >= 1; m >>= 1) s += __shfl_xor(s, m, 64);
        if (l == 0) ((float*)(ws + WS_EN))[u] = s;
    }
}

// ---------------------------------------------------------------------------
// Kernel 2: f16 single-plane MFMA distance GEMM, top-2 candidates per split.
// 2 waves/block, 16 KB LDS -> 4 blocks/CU. sp = blockIdx&3: round-robin
// dispatch keeps one 1 MB f16 E-slice hot per XCD L2.
__global__ __launch_bounds__(128, 2)
void vq_pass1_kernel(const char* __restrict__ ws_c, char* __restrict__ ws) {
    __shared__ __align__(16) _Float16 esh[BNT * CDIM];   // 16 KB

    int tid  = threadIdx.x;
    int lane = tid & 63;
    int w    = tid >> 6;          // wave 0..1 (rows w*32..w*32+31)
    int tm   = lane & 15;
    int q    = lane >> 4;

    int sp = blockIdx.x & 3;      // code split
    int rb = blockIdx.x >> 2;     // row block 0..255
    int r0 = rb * 64;
    int cbase = sp * CODES_PER_SPLIT;

    // ---- prologue: pin z A-fragments (full K, f16) in registers ----
    const _Float16* zh_g = (const _Float16*)(ws_c + WS_ZH);
    v8h zfh[2][8];
    {
        int rowb = r0 + w * 32 + tm;
#pragma unroll
        for (int mi = 0; mi < 2; ++mi)
#pragma unroll
            for (int kc = 0; kc < 8; ++kc)
                zfh[mi][kc] = *(const v8h*)(zh_g +
                    (size_t)(rowb + mi * 16) * CDIM + kc * 32 + q * 8);
    }

    // ---- staging: wave w covers codes w*16..w*16+15, 8 x 1 KB DMAs ----
    const char* egp = ws_c + WS_EH;
    char* ldst = (char*)esh + w * 16 * 512;
    int l5 = lane >> 5, c31 = lane & 31;
    int rel[8];
#pragma unroll
    for (int i = 0; i < 8; ++i) {
        int c = w * 16 + 2 * i + l5;                 // code within tile
        rel[i] = c * 512 + ((c31 ^ (c & 7)) << 4);   // swizzled source offset
    }

    // fragment read offsets (halves): code*256 + swizzled chunk
    int hb  = (tm >> 2) & 1;
    int qx  = q ^ (tm & 3);
    int eb0 = tm * 256 + qx * 8;
    int eb1 = (16 + tm) * 256 + qx * 8;

    const float* en_g = (const float*)(ws_c + WS_EN);

    float rmin1[8], rmin2[8];
    int   ridx1[8], ridx2[8];
#pragma unroll
    for (int s = 0; s < 8; ++s) {
        rmin1[s] = 3e38f; rmin2[s] = 3e38f; ridx1[s] = 0; ridx2[s] = 0;
    }

    const char* tb = egp + (size_t)cbase * 512;

#pragma unroll 1
    for (int tile = 0; tile < NTILES; ++tile) {
        __syncthreads();
#pragma unroll
        for (int i = 0; i < 8; ++i)
            gload_lds16(tb + rel[i], ldst + i * 1024);
        int c0 = cbase + tile * BNT;
        float en0 = en_g[c0 + tm];
        float en1 = en_g[c0 + 16 + tm];
        __syncthreads();
        tb += BNT * 512;

        v4f acc[2][2];
#pragma unroll
        for (int mi = 0; mi < 2; ++mi)
#pragma unroll
            for (int ni = 0; ni < 2; ++ni) acc[mi][ni] = (v4f)0.f;

#pragma unroll
        for (int kc = 0; kc < 8; ++kc) {
            int kx = (kc ^ hb) << 5;
            v8h bh0 = *(const v8h*)&esh[eb0 + kx];
            v8h bh1 = *(const v8h*)&esh[eb1 + kx];
#pragma unroll
            for (int mi = 0; mi < 2; ++mi) {
                acc[mi][0] = __builtin_amdgcn_mfma_f32_16x16x32_f16(zfh[mi][kc], bh0, acc[mi][0], 0, 0, 0);
                acc[mi][1] = __builtin_amdgcn_mfma_f32_16x16x32_f16(zfh[mi][kc], bh1, acc[mi][1], 0, 0, 0);
            }
        }

        // top-2 update: score = ||e||^2 - 2*dot (codes ascending)
#pragma unroll
        for (int ni = 0; ni < 2; ++ni) {
            float en = ni ? en1 : en0;
            int code = c0 + ni * 16 + tm;
#pragma unroll
            for (int mi = 0; mi < 2; ++mi)
#pragma unroll
                for (int r = 0; r < 4; ++r) {
                    float s = fmaf(-2.f, acc[mi][ni][r], en);
                    int slot = mi * 4 + r;
                    if (s < rmin1[slot]) {
                        rmin2[slot] = rmin1[slot]; ridx2[slot] = ridx1[slot];
                        rmin1[slot] = s;           ridx1[slot] = code;
                    } else if (s < rmin2[slot]) {
                        rmin2[slot] = s; ridx2[slot] = code;
                    }
                }
        }
    }

    // ---- merge top-2 across the 16 column-lanes; write candidates ----
#pragma unroll
    for (int slot = 0; slot < 8; ++slot) {
        float v1 = rmin1[slot], v2 = rmin2[slot];
        int   i1 = ridx1[slot], i2 = ridx2[slot];
#pragma unroll
        for (int m = 1; m <= 8; m <<= 1) {
            float b1 = __shfl_xor(v1, m, 64), b2 = __shfl_xor(v2, m, 64);
            int  bi1 = __shfl_xor(i1, m, 64), bi2 = __shfl_xor(i2, m, 64);
            bool swp = (b1 < v1) || (b1 == v1 && bi1 < i1);
            float w1 = swp ? b1 : v1;  int wi1 = swp ? bi1 : i1;
            float l1 = swp ? v1 : b1;  int li1 = swp ? i1 : bi1;
            float w2 = swp ? b2 : v2;  int wi2 = swp ? bi2 : i2;
            bool s2 = (l1 < w2) || (l1 == w2 && li1 < wi2);
            v1 = w1; i1 = wi1;
            v2 = s2 ? l1 : w2; i2 = s2 ? li1 : wi2;
        }
        if (tm == 0) {
            int row = r0 + w * 32 + (slot >> 2) * 16 + q * 4 + (slot & 3);
            char* rec = ws + WS_C + ((size_t)row * NSPLIT + sp) * 16;
            ((float*)rec)[0] = v1; ((int*)rec)[1] = i1;
            ((float*)rec)[2] = v2; ((int*)rec)[3] = i2;
        }
    }
}

// ---------------------------------------------------------------------------
// Kernel 3: exact fp32 re-rank of 8 candidates/row + gather + STE + loss.
// One wave per row (4 rows/block). Lane group g=lane>>3 owns candidate g,
// sub=lane&7 covers 32 dims; shfl-reduce dist, min-select with idx tiebreak.
__global__ void rerank_out_kernel(const float* __restrict__ z,
                                  const float* __restrict__ emb,
                                  const char* __restrict__ ws,
                                  char* __restrict__ ws_w,
                                  float* __restrict__ out) {
    __shared__ float wsum[4];
    int tid = threadIdx.x, lane = tid & 63, w = tid >> 6;
    int row = blockIdx.x * 4 + w;
    int g = lane >> 3, sub = lane & 7;

    // candidate index for this group: split = g>>1, pick = g&1
    const char* rec = ws + WS_C + ((size_t)row * NSPLIT + (g >> 1)) * 16;
    int ci = ((const int*)rec)[1 + 2 * (g & 1)];

    // exact squared distance over dims [sub*32, sub*32+32)
    const float4* e4 = (const float4*)emb;
    const float4* z4 = (const float4*)z;
    float s = 0.f;
#pragma unroll
    for (int j = 0; j < 8; ++j) {
        float4 ev = e4[(size_t)ci * 64 + sub * 8 + j];
        float4 zv = z4[(size_t)row * 64 + sub * 8 + j];
        float dx = ev.x - zv.x, dy = ev.y - zv.y;
        float dz = ev.z - zv.z, dw = ev.w - zv.w;
        s += dx * dx + dy * dy + dz * dz + dw * dw;
    }
#pragma unroll
    for (int m = 1; m <= 4; m <<= 1) s += __shfl_xor(s, m, 64);

    // min over the 8 groups, lowest idx on ties (np.argmin first-min)
    float dv = s; int di = ci;
#pragma unroll
    for (int m = 8; m <= 32; m <<= 1) {
        float d2 = __shfl_xor(dv, m, 64);
        int   i2 = __shfl_xor(di, m, 64);
        if (d2 < dv || (d2 == dv && i2 < di)) { dv = d2; di = i2; }
    }
    if (lane == 0) out[IDXOFF + row] = (float)di;

    // gather winner, STE output, loss partial
    float4 qv = e4[(size_t)di * 64 + lane];
    float4 zv = z4[(size_t)row * 64 + lane];
    float dx = qv.x - zv.x, dy = qv.y - zv.y;
    float dz = qv.z - zv.z, dw = qv.w - zv.w;
    float4 o;   // match reference STE rounding: z + (q - z)
    o.x = zv.x + dx; o.y = zv.y + dy; o.z = zv.z + dz; o.w = zv.w + dw;
    ((float4*)out)[(size_t)row * 64 + lane] = o;
    float ls = dx * dx + dy * dy + dz * dz + dw * dw;
#pragma unroll
    for (int m = 32; m >= 1; m >>= 1) ls += __shfl_xor(ls, m, 64);
    if (lane == 0) wsum[w] = ls;
    __syncthreads();
    if (tid == 0)
        ((float*)(ws_w + WS_PB))[blockIdx.x] =
            wsum[0] + wsum[1] + wsum[2] + wsum[3];
}

// ---------------------------------------------------------------------------
// Kernel 4: sum the 4096 block partials -> vq_loss (plain store, no atomics).
__global__ void loss_sum_kernel(const char* __restrict__ ws,
                                float* __restrict__ out) {
    __shared__ float wsum[4];
    const float* pb = (const float*)(ws + WS_PB);
    int tid = threadIdx.x, lane = tid & 63, w = tid >> 6;
    float s = 0.f;
#pragma unroll
    for (int i = 0; i < 16; ++i) s += pb[i * 256 + tid];
#pragma unroll
    for (int m = 32; m >= 1; m >>= 1) s += __shfl_xor(s, m, 64);
    if (lane == 0) wsum[w] = s;
    __syncthreads();
    if (tid == 0)
        out[LOSS_OFF] = (wsum[0] + wsum[1] + wsum[2] + wsum[3]) *
                        (1.25f / 4194304.f);
}

// ---------------------------------------------------------------------------
extern "C" void kernel_launch(void* const* d_in, const int* in_sizes, int n_in,
                              void* d_out, int out_size, void* d_ws, size_t ws_size,
                              hipStream_t stream) {
    const float* z   = (const float*)d_in[0];
    const float* emb = (const float*)d_in[1];
    float* out = (float*)d_out;
    char*  ws  = (char*)d_ws;   // ~13.7 MB used

    hipLaunchKernelGGL(convert_enorm_kernel, dim3((MROWS + KCODES) / 4),
                       dim3(256), 0, stream, z, emb, ws);
    hipLaunchKernelGGL(vq_pass1_kernel, dim3((MROWS / 64) * NSPLIT), dim3(128),
                       0, stream, ws, ws);
    hipLaunchKernelGGL(rerank_out_kernel, dim3(MROWS / 4), dim3(256),
                       0, stream, z, emb, ws, ws, out);
    hipLaunchKernelGGL(loss_sum_kernel, dim3(1), dim3(256), 0, stream, ws, out);
}

// Round 8
// 217.420 us; speedup vs baseline: 1.5159x; 1.5159x over previous
//
#include <hip/hip_runtime.h>
#include <math.h>

// Problem constants
#define MROWS   16384      // B*N
#define KCODES  8192
#define CDIM    256

// d_out layout (floats): [quantized 4194304][loss 1][indices 16384]
#define LOSS_OFF 4194304
#define IDXOFF   4194305

// ---- ws byte layout (~4.8 MB) ----
#define NSPLIT  8
#define WS_EF   0                            // f16 E plane in FRAGMENT order, 4 MB
#define WS_EN   (WS_EF + KCODES * CDIM * 2)  // float[8192] ||e||^2
#define WS_PI   (WS_EN + KCODES * 4)         // int[NSPLIT*MROWS] split winners

#define CODES_PER_SPLIT (KCODES / NSPLIT)    // 1024
#define STEPS (CODES_PER_SPLIT / 16)         // 64

typedef float    v4f __attribute__((ext_vector_type(4)));
typedef _Float16 v8h __attribute__((ext_vector_type(8)));

// ---------------------------------------------------------------------------
// Kernel 1: permute E fp32 -> f16 fragment-order plane + ||e||^2 + zero loss.
// Fragment order: halves offset = (group*32 + chunk)*128 + (code&15)*8,
// group = code>>4, chunk = kc*4+q (16B unit of K). Pass1's B-load for a wave
// (lanes tm,q) then reads 1024 contiguous bytes per instruction.
__global__ void econv_kernel(const float* __restrict__ emb,
                             char* __restrict__ ws,
                             float* __restrict__ loss_slot) {
    int t = blockIdx.x * 256 + threadIdx.x;   // 0..262143 (one v8h each)
    int j = t >> 5, c = t & 31;               // code, 16B-chunk of K
    const float4* e4 = (const float4*)(emb + (size_t)j * CDIM) + c * 2;
    float4 a = e4[0], b = e4[1];
    v8h h;
    h[0] = (_Float16)a.x; h[1] = (_Float16)a.y;
    h[2] = (_Float16)a.z; h[3] = (_Float16)a.w;
    h[4] = (_Float16)b.x; h[5] = (_Float16)b.y;
    h[6] = (_Float16)b.z; h[7] = (_Float16)b.w;
    _Float16* ef = (_Float16*)(ws + WS_EF);
    *(v8h*)(ef + ((size_t)(j >> 4) * 32 + c) * 128 + (j & 15) * 8) = h;
    float s = a.x * a.x + a.y * a.y + a.z * a.z + a.w * a.w +
              b.x * b.x + b.y * b.y + b.z * b.z + b.w * b.w;
#pragma unroll
    for (int m = 1; m <= 16; m <<= 1) s += __shfl_xor(s, m, 64);
    if (c == 0) ((float*)(ws + WS_EN))[j] = s;
    if (t == 0) *loss_slot = 0.f;
}

// ---------------------------------------------------------------------------
// Kernel 2: f16 MFMA distance pass, NO LDS / NO barriers.
// Wave gw: rows [ (gw>>3)*64, +64 ), codes split gw&7 (1024 codes).
// A-frags (64 rows x full K, f16) converted inline from z into 128 VGPRs.
// B-frags read straight from the fragment-order E plane (L2-resident, 4 MB),
// kc-split double-buffered in registers. Argmin: 3 VALU/score, ties keep
// old (= lower code, codes ascending).
__global__ __launch_bounds__(256, 2)
void vq_pass1_kernel(const float* __restrict__ z,
                     const char* __restrict__ ws_c, char* __restrict__ ws) {
    int tid  = threadIdx.x;
    int lane = tid & 63;
    int w    = tid >> 6;
    int tm   = lane & 15;         // MFMA m/n lane index
    int q    = lane >> 4;         // MFMA k-quad

    int gw = blockIdx.x * 4 + w;
    int sp = gw & 7;              // code split
    int r0 = (gw >> 3) * 64;      // first of 64 rows

    // ---- prologue: convert this wave's A-fragments from fp32 z ----
    v8h zf[4][8];
#pragma unroll
    for (int mi = 0; mi < 4; ++mi) {
        const float* zr = z + (size_t)(r0 + mi * 16 + tm) * CDIM + q * 8;
#pragma unroll
        for (int kc = 0; kc < 8; ++kc) {
            float4 a = *(const float4*)(zr + kc * 32);
            float4 b = *(const float4*)(zr + kc * 32 + 4);
            v8h h;
            h[0] = (_Float16)a.x; h[1] = (_Float16)a.y;
            h[2] = (_Float16)a.z; h[3] = (_Float16)a.w;
            h[4] = (_Float16)b.x; h[5] = (_Float16)b.y;
            h[6] = (_Float16)b.z; h[7] = (_Float16)b.w;
            zf[mi][kc] = h;
        }
    }

    const _Float16* ef  = (const _Float16*)(ws_c + WS_EF);
    const float*    en_g = (const float*)(ws_c + WS_EN);
    // per-lane B base: group (sp*64) + chunk q + code-lane tm
    const _Float16* bbase = ef + (size_t)(sp * 64) * 4096 + q * 128 + tm * 8;

    float rmin[16];
    int   ridx[16];
#pragma unroll
    for (int s = 0; s < 16; ++s) { rmin[s] = 3e38f; ridx[s] = 0; }

    // double-buffered B fragments (kc 0-3 / kc 4-7)
    v8h b0[4], b1[4];
#pragma unroll
    for (int kc = 0; kc < 4; ++kc) b0[kc] = *(const v8h*)(bbase + kc * 512);
#pragma unroll
    for (int kc = 0; kc < 4; ++kc) b1[kc] = *(const v8h*)(bbase + 2048 + kc * 512);
    float enr = en_g[sp * 1024 + tm];

#pragma unroll 1
    for (int st = 0; st < STEPS; ++st) {
        int stn = (st < STEPS - 1) ? st + 1 : st;      // harmless re-load on last
        const _Float16* nb = bbase + (size_t)stn * 4096;

        v4f acc[4];
#pragma unroll
        for (int mi = 0; mi < 4; ++mi)
            acc[mi] = __builtin_amdgcn_mfma_f32_16x16x32_f16(zf[mi][0], b0[0], (v4f)0.f, 0, 0, 0);
#pragma unroll
        for (int kc = 1; kc < 4; ++kc)
#pragma unroll
            for (int mi = 0; mi < 4; ++mi)
                acc[mi] = __builtin_amdgcn_mfma_f32_16x16x32_f16(zf[mi][kc], b0[kc], acc[mi], 0, 0, 0);
#pragma unroll
        for (int kc = 0; kc < 4; ++kc) b0[kc] = *(const v8h*)(nb + kc * 512);
#pragma unroll
        for (int kc = 0; kc < 4; ++kc)
#pragma unroll
            for (int mi = 0; mi < 4; ++mi)
                acc[mi] = __builtin_amdgcn_mfma_f32_16x16x32_f16(zf[mi][4 + kc], b1[kc], acc[mi], 0, 0, 0);
#pragma unroll
        for (int kc = 0; kc < 4; ++kc) b1[kc] = *(const v8h*)(nb + 2048 + kc * 512);
        float enn = en_g[sp * 1024 + stn * 16 + tm];

        int code = sp * 1024 + st * 16 + tm;
#pragma unroll
        for (int mi = 0; mi < 4; ++mi)
#pragma unroll
            for (int r = 0; r < 4; ++r) {
                float s = fmaf(-2.f, acc[mi][r], enr);
                int slot = mi * 4 + r;
                bool lt = s < rmin[slot];
                ridx[slot] = lt ? code : ridx[slot];
                rmin[slot] = fminf(s, rmin[slot]);
            }
        enr = enn;
    }

    // ---- reduce across the 16 column-lanes (tm); write split winner idx ----
#pragma unroll
    for (int slot = 0; slot < 16; ++slot) {
        float bv = rmin[slot];
        int   bi = ridx[slot];
#pragma unroll
        for (int m = 1; m <= 8; m <<= 1) {
            float v2 = __shfl_xor(bv, m, 64);
            int   i2 = __shfl_xor(bi, m, 64);
            if (v2 < bv || (v2 == bv && i2 < bi)) { bv = v2; bi = i2; }
        }
        if (tm == 0) {
            int row = r0 + (slot >> 2) * 16 + q * 4 + (slot & 3);
            ((int*)(ws + WS_PI))[sp * MROWS + row] = bi;
        }
    }
}

// ---------------------------------------------------------------------------
// Kernel 3: exact fp32 re-rank of the 8 split winners per row + gather +
// STE output + 1.25*MSE loss. Grid 256 x 256thr, 16 row-iters per wave;
// one atomicAdd per block.
__global__ void rerank_out_kernel(const float* __restrict__ z,
                                  const float* __restrict__ emb,
                                  const char* __restrict__ ws,
                                  float* __restrict__ out) {
    __shared__ float wsum[4];
    const int* pi = (const int*)(ws + WS_PI);
    int tid = threadIdx.x, lane = tid & 63, w = tid >> 6;
    int g = lane >> 3, sub = lane & 7;    // candidate group, dim-slice
    const float4* e4 = (const float4*)emb;
    const float4* z4 = (const float4*)z;
    float lsum = 0.f;

#pragma unroll 1
    for (int it = 0; it < 16; ++it) {
        int row = it * 1024 + blockIdx.x * 4 + w;
        int ci = pi[g * MROWS + row];
        // exact squared distance over dims [sub*32, sub*32+32)
        float s = 0.f;
#pragma unroll
        for (int j = 0; j < 8; ++j) {
            float4 ev = e4[(size_t)ci * 64 + sub * 8 + j];
            float4 zv = z4[(size_t)row * 64 + sub * 8 + j];
            float dx = ev.x - zv.x, dy = ev.y - zv.y;
            float dz = ev.z - zv.z, dw = ev.w - zv.w;
            s += dx * dx + dy * dy + dz * dz + dw * dw;
        }
#pragma unroll
        for (int m = 1; m <= 4; m <<= 1) s += __shfl_xor(s, m, 64);
        // min over the 8 groups, lowest idx on ties (np first-min)
        float dv = s; int di = ci;
#pragma unroll
        for (int m = 8; m <= 32; m <<= 1) {
            float d2 = __shfl_xor(dv, m, 64);
            int   i2 = __shfl_xor(di, m, 64);
            if (d2 < dv || (d2 == dv && i2 < di)) { dv = d2; di = i2; }
        }
        if (lane == 0) out[IDXOFF + row] = (float)di;
        // gather winner, STE output, loss partial
        float4 qv = e4[(size_t)di * 64 + lane];
        float4 zv = z4[(size_t)row * 64 + lane];
        float dx = qv.x - zv.x, dy = qv.y - zv.y;
        float dz = qv.z - zv.z, dw = qv.w - zv.w;
        float4 o;   // match reference STE rounding: z + (q - z)
        o.x = zv.x + dx; o.y = zv.y + dy; o.z = zv.z + dz; o.w = zv.w + dw;
        ((float4*)out)[(size_t)row * 64 + lane] = o;
        lsum += dx * dx + dy * dy + dz * dz + dw * dw;
    }

#pragma unroll
    for (int m = 32; m >= 1; m >>= 1) lsum += __shfl_xor(lsum, m, 64);
    if (lane == 0) wsum[w] = lsum;
    __syncthreads();
    if (tid == 0)
        atomicAdd(out + LOSS_OFF,
                  (wsum[0] + wsum[1] + wsum[2] + wsum[3]) * (1.25f / 4194304.f));
}

// ---------------------------------------------------------------------------
extern "C" void kernel_launch(void* const* d_in, const int* in_sizes, int n_in,
                              void* d_out, int out_size, void* d_ws, size_t ws_size,
                              hipStream_t stream) {
    const float* z   = (const float*)d_in[0];
    const float* emb = (const float*)d_in[1];
    float* out = (float*)d_out;
    char*  ws  = (char*)d_ws;   // ~4.8 MB used

    hipLaunchKernelGGL(econv_kernel, dim3(KCODES * CDIM / 8 / 256), dim3(256),
                       0, stream, emb, ws, out + LOSS_OFF);
    hipLaunchKernelGGL(vq_pass1_kernel, dim3((MROWS / 64) * NSPLIT / 4), dim3(256),
                       0, stream, z, ws, ws);
    hipLaunchKernelGGL(rerank_out_kernel, dim3(256), dim3(256),
                       0, stream, z, emb, ws, out);
}

// Round 9
// 209.704 us; speedup vs baseline: 1.5717x; 1.0368x over previous
//
#include <hip/hip_runtime.h>
#include <math.h>

// Problem constants
#define MROWS   16384      // B*N
#define KCODES  8192
#define CDIM    256

// d_out layout (floats): [quantized 4194304][loss 1][indices 16384]
#define LOSS_OFF 4194304
#define IDXOFF   4194305

// ---- ws byte layout (~4.8 MB) ----
#define NSPLIT  8
#define WS_EF   0                            // f16 E plane in FRAGMENT order, 4 MB
#define WS_EN   (WS_EF + KCODES * CDIM * 2)  // float[8192] ||e||^2
#define WS_PI   (WS_EN + KCODES * 4)         // int[NSPLIT*MROWS] split winners

#define CODES_PER_SPLIT (KCODES / NSPLIT)    // 1024
#define STEPS (CODES_PER_SPLIT / 16)         // 64

typedef float    v4f __attribute__((ext_vector_type(4)));
typedef _Float16 v8h __attribute__((ext_vector_type(8)));

// ---------------------------------------------------------------------------
// Kernel 1: permute E fp32 -> f16 fragment-order plane + ||e||^2 + zero loss.
// Fragment order: halves offset = (group*32 + chunk)*128 + (code&15)*8,
// group = code>>4, chunk = kc*4+q (16B unit of K). Pass1's B-load for a wave
// (lanes tm,q) then reads 1024 contiguous bytes per instruction.
__global__ void econv_kernel(const float* __restrict__ emb,
                             char* __restrict__ ws,
                             float* __restrict__ loss_slot) {
    int t = blockIdx.x * 256 + threadIdx.x;   // 0..262143 (one v8h each)
    int j = t >> 5, c = t & 31;               // code, 16B-chunk of K
    const float4* e4 = (const float4*)(emb + (size_t)j * CDIM) + c * 2;
    float4 a = e4[0], b = e4[1];
    v8h h;
    h[0] = (_Float16)a.x; h[1] = (_Float16)a.y;
    h[2] = (_Float16)a.z; h[3] = (_Float16)a.w;
    h[4] = (_Float16)b.x; h[5] = (_Float16)b.y;
    h[6] = (_Float16)b.z; h[7] = (_Float16)b.w;
    _Float16* ef = (_Float16*)(ws + WS_EF);
    *(v8h*)(ef + ((size_t)(j >> 4) * 32 + c) * 128 + (j & 15) * 8) = h;
    float s = a.x * a.x + a.y * a.y + a.z * a.z + a.w * a.w +
              b.x * b.x + b.y * b.y + b.z * b.z + b.w * b.w;
#pragma unroll
    for (int m = 1; m <= 16; m <<= 1) s += __shfl_xor(s, m, 64);
    if (c == 0) ((float*)(ws + WS_EN))[j] = s;
    if (t == 0) *loss_slot = 0.f;
}

// ---------------------------------------------------------------------------
// Kernel 2: f16 MFMA distance pass, NO LDS / NO barriers.
// Block = 4 waves, 128 rows x ONE split (sp = blockIdx&7 -> XCD-local 0.5 MB
// E-slice). Wave w owns rows r0+w*32; all 4 waves issue IDENTICAL B-load
// streams -> 3 of 4 hit L1. zf[2][8] = 64 VGPRs; total ~140 regs, bounds
// (256,3) caps at ~170 -> no spills (round 8's 64-row wave spilled at 128).
__global__ __launch_bounds__(256, 3)
void vq_pass1_kernel(const float* __restrict__ z,
                     const char* __restrict__ ws_c, char* __restrict__ ws) {
    int tid  = threadIdx.x;
    int lane = tid & 63;
    int w    = tid >> 6;
    int tm   = lane & 15;         // MFMA m/n lane index
    int q    = lane >> 4;         // MFMA k-quad

    int sp = blockIdx.x & 7;              // code split (shared by block)
    int r0 = (blockIdx.x >> 3) * 128 + w * 32;

    // ---- prologue: convert this wave's A-fragments from fp32 z ----
    v8h zf[2][8];
#pragma unroll
    for (int mi = 0; mi < 2; ++mi) {
        const float* zr = z + (size_t)(r0 + mi * 16 + tm) * CDIM + q * 8;
#pragma unroll
        for (int kc = 0; kc < 8; ++kc) {
            float4 a = *(const float4*)(zr + kc * 32);
            float4 b = *(const float4*)(zr + kc * 32 + 4);
            v8h h;
            h[0] = (_Float16)a.x; h[1] = (_Float16)a.y;
            h[2] = (_Float16)a.z; h[3] = (_Float16)a.w;
            h[4] = (_Float16)b.x; h[5] = (_Float16)b.y;
            h[6] = (_Float16)b.z; h[7] = (_Float16)b.w;
            zf[mi][kc] = h;
        }
    }

    const _Float16* ef   = (const _Float16*)(ws_c + WS_EF);
    const float*    en_g = (const float*)(ws_c + WS_EN);
    // per-lane B base: group (sp*64) + chunk q + code-lane tm
    const _Float16* bbase = ef + (size_t)(sp * 64) * 4096 + q * 128 + tm * 8;

    float rmin[8];
    int   ridx[8];
#pragma unroll
    for (int s = 0; s < 8; ++s) { rmin[s] = 3e38f; ridx[s] = 0; }

    // double-buffered B fragments (kc 0-3 / kc 4-7)
    v8h b0[4], b1[4];
#pragma unroll
    for (int kc = 0; kc < 4; ++kc) b0[kc] = *(const v8h*)(bbase + kc * 512);
#pragma unroll
    for (int kc = 0; kc < 4; ++kc) b1[kc] = *(const v8h*)(bbase + 2048 + kc * 512);
    float enr = en_g[sp * 1024 + tm];

#pragma unroll 1
    for (int st = 0; st < STEPS; ++st) {
        int stn = (st < STEPS - 1) ? st + 1 : st;      // harmless re-load on last
        const _Float16* nb = bbase + (size_t)stn * 4096;

        v4f acc[2];
#pragma unroll
        for (int mi = 0; mi < 2; ++mi)
            acc[mi] = __builtin_amdgcn_mfma_f32_16x16x32_f16(zf[mi][0], b0[0], (v4f)0.f, 0, 0, 0);
#pragma unroll
        for (int kc = 1; kc < 4; ++kc)
#pragma unroll
            for (int mi = 0; mi < 2; ++mi)
                acc[mi] = __builtin_amdgcn_mfma_f32_16x16x32_f16(zf[mi][kc], b0[kc], acc[mi], 0, 0, 0);
#pragma unroll
        for (int kc = 0; kc < 4; ++kc) b0[kc] = *(const v8h*)(nb + kc * 512);
#pragma unroll
        for (int kc = 0; kc < 4; ++kc)
#pragma unroll
            for (int mi = 0; mi < 2; ++mi)
                acc[mi] = __builtin_amdgcn_mfma_f32_16x16x32_f16(zf[mi][4 + kc], b1[kc], acc[mi], 0, 0, 0);
#pragma unroll
        for (int kc = 0; kc < 4; ++kc) b1[kc] = *(const v8h*)(nb + 2048 + kc * 512);
        float enn = en_g[sp * 1024 + stn * 16 + tm];

        int code = sp * 1024 + st * 16 + tm;
#pragma unroll
        for (int mi = 0; mi < 2; ++mi)
#pragma unroll
            for (int r = 0; r < 4; ++r) {
                float s = fmaf(-2.f, acc[mi][r], enr);
                int slot = mi * 4 + r;
                bool lt = s < rmin[slot];               // strict: ties keep lower code
                ridx[slot] = lt ? code : ridx[slot];
                rmin[slot] = fminf(s, rmin[slot]);
            }
        enr = enn;
    }

    // ---- reduce across the 16 column-lanes (tm); write split winner idx ----
#pragma unroll
    for (int slot = 0; slot < 8; ++slot) {
        float bv = rmin[slot];
        int   bi = ridx[slot];
#pragma unroll
        for (int m = 1; m <= 8; m <<= 1) {
            float v2 = __shfl_xor(bv, m, 64);
            int   i2 = __shfl_xor(bi, m, 64);
            if (v2 < bv || (v2 == bv && i2 < bi)) { bv = v2; bi = i2; }
        }
        if (tm == 0) {
            int row = r0 + (slot >> 2) * 16 + q * 4 + (slot & 3);
            ((int*)(ws + WS_PI))[sp * MROWS + row] = bi;
        }
    }
}

// ---------------------------------------------------------------------------
// Kernel 3: exact fp32 re-rank of the 8 split winners per row + gather +
// STE output + 1.25*MSE loss. Grid 256 x 256thr, 16 row-iters per wave;
// one atomicAdd per block.
__global__ void rerank_out_kernel(const float* __restrict__ z,
                                  const float* __restrict__ emb,
                                  const char* __restrict__ ws,
                                  float* __restrict__ out) {
    __shared__ float wsum[4];
    const int* pi = (const int*)(ws + WS_PI);
    int tid = threadIdx.x, lane = tid & 63, w = tid >> 6;
    int g = lane >> 3, sub = lane & 7;    // candidate group, dim-slice
    const float4* e4 = (const float4*)emb;
    const float4* z4 = (const float4*)z;
    float lsum = 0.f;

#pragma unroll 1
    for (int it = 0; it < 16; ++it) {
        int row = it * 1024 + blockIdx.x * 4 + w;
        int ci = pi[g * MROWS + row];
        // exact squared distance over dims [sub*32, sub*32+32)
        float s = 0.f;
#pragma unroll
        for (int j = 0; j < 8; ++j) {
            float4 ev = e4[(size_t)ci * 64 + sub * 8 + j];
            float4 zv = z4[(size_t)row * 64 + sub * 8 + j];
            float dx = ev.x - zv.x, dy = ev.y - zv.y;
            float dz = ev.z - zv.z, dw = ev.w - zv.w;
            s += dx * dx + dy * dy + dz * dz + dw * dw;
        }
#pragma unroll
        for (int m = 1; m <= 4; m <<= 1) s += __shfl_xor(s, m, 64);
        // min over the 8 groups, lowest idx on ties (np first-min)
        float dv = s; int di = ci;
#pragma unroll
        for (int m = 8; m <= 32; m <<= 1) {
            float d2 = __shfl_xor(dv, m, 64);
            int   i2 = __shfl_xor(di, m, 64);
            if (d2 < dv || (d2 == dv && i2 < di)) { dv = d2; di = i2; }
        }
        if (lane == 0) out[IDXOFF + row] = (float)di;
        // gather winner, STE output, loss partial
        float4 qv = e4[(size_t)di * 64 + lane];
        float4 zv = z4[(size_t)row * 64 + lane];
        float dx = qv.x - zv.x, dy = qv.y - zv.y;
        float dz = qv.z - zv.z, dw = qv.w - zv.w;
        float4 o;   // match reference STE rounding: z + (q - z)
        o.x = zv.x + dx; o.y = zv.y + dy; o.z = zv.z + dz; o.w = zv.w + dw;
        ((float4*)out)[(size_t)row * 64 + lane] = o;
        lsum += dx * dx + dy * dy + dz * dz + dw * dw;
    }

#pragma unroll
    for (int m = 32; m >= 1; m >>= 1) lsum += __shfl_xor(lsum, m, 64);
    if (lane == 0) wsum[w] = lsum;
    __syncthreads();
    if (tid == 0)
        atomicAdd(out + LOSS_OFF,
                  (wsum[0] + wsum[1] + wsum[2] + wsum[3]) * (1.25f / 4194304.f));
}

// ---------------------------------------------------------------------------
extern "C" void kernel_launch(void* const* d_in, const int* in_sizes, int n_in,
                              void* d_out, int out_size, void* d_ws, size_t ws_size,
                              hipStream_t stream) {
    const float* z   = (const float*)d_in[0];
    const float* emb = (const float*)d_in[1];
    float* out = (float*)d_out;
    char*  ws  = (char*)d_ws;   // ~4.8 MB used

    hipLaunchKernelGGL(econv_kernel, dim3(KCODES * CDIM / 8 / 256), dim3(256),
                       0, stream, emb, ws, out + LOSS_OFF);
    hipLaunchKernelGGL(vq_pass1_kernel, dim3((MROWS / 128) * NSPLIT), dim3(256),
                       0, stream, z, ws, ws);
    hipLaunchKernelGGL(rerank_out_kernel, dim3(256), dim3(256),
                       0, stream, z, emb, ws, out);
}

// Round 10
// 205.635 us; speedup vs baseline: 1.6028x; 1.0198x over previous
//
#include <hip/hip_runtime.h>
#include <math.h>

// Problem constants
#define MROWS   16384      // B*N
#define KCODES  8192
#define CDIM    256

// d_out layout (floats): [quantized 4194304][loss 1][indices 16384]
#define LOSS_OFF 4194304
#define IDXOFF   4194305

// ---- ws byte layout (~13.2 MB) ----
#define NSPLIT  8
#define WS_EF   0                            // f16 E plane, FRAGMENT order, 4 MB
#define WS_ZF   (WS_EF + KCODES * CDIM * 2)  // f16 z plane, FRAGMENT order, 8.4 MB
#define WS_EN   (WS_ZF + MROWS * CDIM * 2)   // float[8192] ||e||^2
#define WS_PI   (WS_EN + KCODES * 4)         // int[NSPLIT*MROWS] split winners

#define CODES_PER_SPLIT (KCODES / NSPLIT)    // 1024
#define STEPS (CODES_PER_SPLIT / 16)         // 64

typedef float    v4f __attribute__((ext_vector_type(4)));
typedef _Float16 v8h __attribute__((ext_vector_type(8)));

// ---------------------------------------------------------------------------
// Kernel 1: fp32 -> f16 fragment-order planes for BOTH z and E; ||e||^2.
// Fragment order (halves): off = ((row>>4)*32 + chunk)*128 + (row&15)*8,
// chunk = 16B-unit of K (kc*4+q). A wave's fragment load in pass1 is then
// 1024 contiguous bytes per instruction.
__global__ void conv_kernel(const float* __restrict__ z,
                            const float* __restrict__ emb,
                            char* __restrict__ ws,
                            float* __restrict__ loss_slot) {
    int t = blockIdx.x * 256 + threadIdx.x;   // one v8h each
    const int NZ = MROWS * 32;                // 524288 z v8h units
    const float4* s4;
    _Float16* dst;
    int j, c;
    bool isE = (t >= NZ);
    if (!isE) {
        j = t >> 5; c = t & 31;
        s4 = (const float4*)(z + (size_t)j * CDIM) + c * 2;
        dst = (_Float16*)(ws + WS_ZF);
    } else {
        int u = t - NZ;
        j = u >> 5; c = u & 31;
        s4 = (const float4*)(emb + (size_t)j * CDIM) + c * 2;
        dst = (_Float16*)(ws + WS_EF);
    }
    float4 a = s4[0], b = s4[1];
    v8h h;
    h[0] = (_Float16)a.x; h[1] = (_Float16)a.y;
    h[2] = (_Float16)a.z; h[3] = (_Float16)a.w;
    h[4] = (_Float16)b.x; h[5] = (_Float16)b.y;
    h[6] = (_Float16)b.z; h[7] = (_Float16)b.w;
    *(v8h*)(dst + ((size_t)(j >> 4) * 32 + c) * 128 + (j & 15) * 8) = h;
    if (isE) {
        float s = a.x * a.x + a.y * a.y + a.z * a.z + a.w * a.w +
                  b.x * b.x + b.y * b.y + b.z * b.z + b.w * b.w;
#pragma unroll
        for (int m = 1; m <= 16; m <<= 1) s += __shfl_xor(s, m, 64);
        if (c == 0) ((float*)(ws + WS_EN))[j] = s;
    }
    if (t == 0) *loss_slot = 0.f;
}

// ---------------------------------------------------------------------------
// Kernel 2: f16 MFMA distance pass, NO LDS / NO barriers. 64 rows/wave.
// Grid 512. XCD banding (round-robin dispatch: XCD = b&7): rb = (b&7)*8 +
// ((b>>3)&7) -> each XCD covers one contiguous 2048-row band (1.05 MB zf,
// L2-resident); sp = b>>6 sweeps the 8 code splits in phase chip-wide.
// 32 MFMAs per 8 B-loads (2x the ratio of round 9) halves L2 B-traffic.
__global__ __launch_bounds__(256, 2)
void vq_pass1_kernel(const char* __restrict__ ws_c, char* __restrict__ ws) {
    int tid  = threadIdx.x;
    int lane = tid & 63;
    int w    = tid >> 6;
    int tm   = lane & 15;         // MFMA m/n lane index
    int q    = lane >> 4;         // MFMA k-quad

    int b  = blockIdx.x;
    int rb = (b & 7) * 8 + ((b >> 3) & 7);   // row block (256 rows)
    int sp = b >> 6;                          // code split
    int r0 = rb * 256 + w * 64;               // this wave's 64 rows

    // ---- prologue: load A-fragments (64 rows x full K) from zf plane ----
    const _Float16* zf_g = (const _Float16*)(ws_c + WS_ZF);
    v8h zf[4][8];
#pragma unroll
    for (int mi = 0; mi < 4; ++mi) {
        const _Float16* zr = zf_g + (size_t)((r0 >> 4) + mi) * 4096 + q * 128 + tm * 8;
#pragma unroll
        for (int kc = 0; kc < 8; ++kc)
            zf[mi][kc] = *(const v8h*)(zr + kc * 512);
    }

    const _Float16* ef   = (const _Float16*)(ws_c + WS_EF);
    const float*    en_g = (const float*)(ws_c + WS_EN);
    const _Float16* bbase = ef + (size_t)(sp * 64) * 4096 + q * 128 + tm * 8;

    float rmin[16];
    int   ridx[16];
#pragma unroll
    for (int s = 0; s < 16; ++s) { rmin[s] = 3e38f; ridx[s] = 0; }

    // double-buffered B fragments (kc 0-3 / kc 4-7)
    v8h b0[4], b1[4];
#pragma unroll
    for (int kc = 0; kc < 4; ++kc) b0[kc] = *(const v8h*)(bbase + kc * 512);
#pragma unroll
    for (int kc = 0; kc < 4; ++kc) b1[kc] = *(const v8h*)(bbase + 2048 + kc * 512);
    float enr = en_g[sp * 1024 + tm];

#pragma unroll 1
    for (int st = 0; st < STEPS; ++st) {
        int stn = (st < STEPS - 1) ? st + 1 : st;      // harmless re-load on last
        const _Float16* nb = bbase + (size_t)stn * 4096;

        v4f acc[4];
#pragma unroll
        for (int mi = 0; mi < 4; ++mi)
            acc[mi] = __builtin_amdgcn_mfma_f32_16x16x32_f16(zf[mi][0], b0[0], (v4f)0.f, 0, 0, 0);
#pragma unroll
        for (int kc = 1; kc < 4; ++kc)
#pragma unroll
            for (int mi = 0; mi < 4; ++mi)
                acc[mi] = __builtin_amdgcn_mfma_f32_16x16x32_f16(zf[mi][kc], b0[kc], acc[mi], 0, 0, 0);
#pragma unroll
        for (int kc = 0; kc < 4; ++kc) b0[kc] = *(const v8h*)(nb + kc * 512);
#pragma unroll
        for (int kc = 0; kc < 4; ++kc)
#pragma unroll
            for (int mi = 0; mi < 4; ++mi)
                acc[mi] = __builtin_amdgcn_mfma_f32_16x16x32_f16(zf[mi][4 + kc], b1[kc], acc[mi], 0, 0, 0);
#pragma unroll
        for (int kc = 0; kc < 4; ++kc) b1[kc] = *(const v8h*)(nb + 2048 + kc * 512);
        float enn = en_g[sp * 1024 + stn * 16 + tm];

        int code = sp * 1024 + st * 16 + tm;
#pragma unroll
        for (int mi = 0; mi < 4; ++mi)
#pragma unroll
            for (int r = 0; r < 4; ++r) {
                float s = fmaf(-2.f, acc[mi][r], enr);
                int slot = mi * 4 + r;
                bool lt = s < rmin[slot];               // strict: ties keep lower code
                ridx[slot] = lt ? code : ridx[slot];
                rmin[slot] = fminf(s, rmin[slot]);
            }
        enr = enn;
    }

    // ---- reduce across the 16 column-lanes (tm); write split winner idx ----
#pragma unroll
    for (int slot = 0; slot < 16; ++slot) {
        float bv = rmin[slot];
        int   bi = ridx[slot];
#pragma unroll
        for (int m = 1; m <= 8; m <<= 1) {
            float v2 = __shfl_xor(bv, m, 64);
            int   i2 = __shfl_xor(bi, m, 64);
            if (v2 < bv || (v2 == bv && i2 < bi)) { bv = v2; bi = i2; }
        }
        if (tm == 0) {
            int row = r0 + (slot >> 2) * 16 + q * 4 + (slot & 3);
            ((int*)(ws + WS_PI))[sp * MROWS + row] = bi;
        }
    }
}

// ---------------------------------------------------------------------------
// Kernel 3: exact fp32 re-rank of the 8 split winners per row + gather +
// STE output + 1.25*MSE loss. Grid 1024 x 256thr, 4 row-iters per wave.
__global__ void rerank_out_kernel(const float* __restrict__ z,
                                  const float* __restrict__ emb,
                                  const char* __restrict__ ws,
                                  float* __restrict__ out) {
    __shared__ float wsum[4];
    const int* pi = (const int*)(ws + WS_PI);
    int tid = threadIdx.x, lane = tid & 63, w = tid >> 6;
    int g = lane >> 3, sub = lane & 7;    // candidate group, dim-slice
    const float4* e4 = (const float4*)emb;
    const float4* z4 = (const float4*)z;
    float lsum = 0.f;

#pragma unroll 1
    for (int it = 0; it < 4; ++it) {
        int row = it * 4096 + blockIdx.x * 4 + w;
        int ci = pi[g * MROWS + row];
        // exact squared distance over dims [sub*32, sub*32+32)
        float s = 0.f;
#pragma unroll
        for (int j = 0; j < 8; ++j) {
            float4 ev = e4[(size_t)ci * 64 + sub * 8 + j];
            float4 zv = z4[(size_t)row * 64 + sub * 8 + j];
            float dx = ev.x - zv.x, dy = ev.y - zv.y;
            float dz = ev.z - zv.z, dw = ev.w - zv.w;
            s += dx * dx + dy * dy + dz * dz + dw * dw;
        }
#pragma unroll
        for (int m = 1; m <= 4; m <<= 1) s += __shfl_xor(s, m, 64);
        // min over the 8 groups, lowest idx on ties (np first-min)
        float dv = s; int di = ci;
#pragma unroll
        for (int m = 8; m <= 32; m <<= 1) {
            float d2 = __shfl_xor(dv, m, 64);
            int   i2 = __shfl_xor(di, m, 64);
            if (d2 < dv || (d2 == dv && i2 < di)) { dv = d2; di = i2; }
        }
        if (lane == 0) out[IDXOFF + row] = (float)di;
        // gather winner, STE output, loss partial
        float4 qv = e4[(size_t)di * 64 + lane];
        float4 zv = z4[(size_t)row * 64 + lane];
        float dx = qv.x - zv.x, dy = qv.y - zv.y;
        float dz = qv.z - zv.z, dw = qv.w - zv.w;
        float4 o;   // match reference STE rounding: z + (q - z)
        o.x = zv.x + dx; o.y = zv.y + dy; o.z = zv.z + dz; o.w = zv.w + dw;
        ((float4*)out)[(size_t)row * 64 + lane] = o;
        lsum += dx * dx + dy * dy + dz * dz + dw * dw;
    }

#pragma unroll
    for (int m = 32; m >= 1; m >>= 1) lsum += __shfl_xor(lsum, m, 64);
    if (lane == 0) wsum[w] = lsum;
    __syncthreads();
    if (tid == 0)
        atomicAdd(out + LOSS_OFF,
                  (wsum[0] + wsum[1] + wsum[2] + wsum[3]) * (1.25f / 4194304.f));
}

// ---------------------------------------------------------------------------
extern "C" void kernel_launch(void* const* d_in, const int* in_sizes, int n_in,
                              void* d_out, int out_size, void* d_ws, size_t ws_size,
                              hipStream_t stream) {
    const float* z   = (const float*)d_in[0];
    const float* emb = (const float*)d_in[1];
    float* out = (float*)d_out;
    char*  ws  = (char*)d_ws;   // ~13.2 MB used

    hipLaunchKernelGGL(conv_kernel, dim3((MROWS + KCODES) * 32 / 256), dim3(256),
                       0, stream, z, emb, ws, out + LOSS_OFF);
    hipLaunchKernelGGL(vq_pass1_kernel, dim3((MROWS / 256) * NSPLIT), dim3(256),
                       0, stream, ws, ws);
    hipLaunchKernelGGL(rerank_out_kernel, dim3(1024), dim3(256),
                       0, stream, z, emb, ws, out);
}